// Round 1
// baseline (1291.089 us; speedup 1.0000x reference)
//
#include <hip/hip_runtime.h>
#include <math.h>

#define B_DIM  32
#define C_DIM  512
#define N_DIM  1024
#define LOG2E  1.44269504088896340736f

// ---------------------------------------------------------------------------
// Projection GEMM: Y[b][o][n] = sum_c W[o][c] * X[b][c][n] + bias[o]
// BM=BN=128, BK=16, 256 threads, 8x8 micro-tile, fp32 vector FMA.
//   QK=true : O=128; rows 0..63 use (Wa,ba)=(Wq,bq), rows 64..127 use (Wb,bb)=(Wk,bk)
//   QK=false: O=512; all rows use (Wa,ba)=(Wv,bv)
// ---------------------------------------------------------------------------
template<bool QK>
__global__ __launch_bounds__(256) void proj_kernel(
    const float* __restrict__ X,
    const float* __restrict__ Wa, const float* __restrict__ ba,
    const float* __restrict__ Wb, const float* __restrict__ bb,
    float* __restrict__ Y)
{
    const int O = QK ? 128 : 512;
    __shared__ __align__(16) float As[16][132];   // [k][o], padded (132: 16B-aligned rows, 2-way max on writes)
    __shared__ __align__(16) float Bs[16][128];   // [k][n]

    const int b  = blockIdx.z;
    const int o0 = blockIdx.y * 128;
    const int n0 = blockIdx.x * 128;
    const int t  = threadIdx.x;
    const int tx = t & 15;         // output cols tx*4, tx*4+64
    const int ty = t >> 4;         // output rows ty*4, ty*4+64

    const float* Xb = X + (size_t)b * C_DIM * N_DIM;

    float acc[8][8];
    #pragma unroll
    for (int i = 0; i < 8; ++i)
        #pragma unroll
        for (int j = 0; j < 8; ++j) acc[i][j] = 0.0f;

    const int ai = t >> 2;   // 0..63  A-load row
    const int ak = t & 3;    // 0..3   A-load float4 col
    const int lk = t >> 5;   // 0..7   B-load row
    const int ln = t & 31;   // 0..31  B-load float4 col

    for (int k0 = 0; k0 < C_DIM; k0 += 16) {
        // ---- A tile: W[o0+i][k0..k0+15] -> As[k][i] (transposed)
        #pragma unroll
        for (int p = 0; p < 2; ++p) {
            const int i = ai + 64 * p;
            const float* Wrow;
            if (QK) Wrow = (p == 0) ? (Wa + (size_t)i * C_DIM)
                                    : (Wb + (size_t)(i - 64) * C_DIM);
            else    Wrow = Wa + (size_t)(o0 + i) * C_DIM;
            const float4 av = *(const float4*)(Wrow + k0 + ak * 4);
            As[ak*4+0][i] = av.x;  As[ak*4+1][i] = av.y;
            As[ak*4+2][i] = av.z;  As[ak*4+3][i] = av.w;
        }
        // ---- B tile: X[b][k0+k][n0..n0+127] -> Bs[k][n] (coalesced float4)
        #pragma unroll
        for (int p = 0; p < 2; ++p) {
            const int k = lk + 8 * p;
            *(float4*)&Bs[k][ln*4] =
                *(const float4*)&Xb[(size_t)(k0 + k) * N_DIM + n0 + ln*4];
        }
        __syncthreads();
        #pragma unroll
        for (int k = 0; k < 16; ++k) {
            const float4 a0 = *(const float4*)&As[k][ty*4];
            const float4 a1 = *(const float4*)&As[k][ty*4 + 64];
            const float4 b0 = *(const float4*)&Bs[k][tx*4];
            const float4 b1 = *(const float4*)&Bs[k][tx*4 + 64];
            const float av[8] = {a0.x,a0.y,a0.z,a0.w,a1.x,a1.y,a1.z,a1.w};
            const float bv[8] = {b0.x,b0.y,b0.z,b0.w,b1.x,b1.y,b1.z,b1.w};
            #pragma unroll
            for (int i = 0; i < 8; ++i)
                #pragma unroll
                for (int j = 0; j < 8; ++j)
                    acc[i][j] = fmaf(av[i], bv[j], acc[i][j]);
        }
        __syncthreads();
    }
    // ---- epilogue: add bias, store float4
    #pragma unroll
    for (int i = 0; i < 8; ++i) {
        const int o = o0 + ty*4 + (i & 3) + (i >> 2) * 64;
        float bias;
        if (QK) bias = (i < 4) ? ba[o] : bb[o - 64];
        else    bias = ba[o];
        float* Yrow = Y + ((size_t)b * O + o) * N_DIM + n0;
        const float4 s0 = make_float4(acc[i][0]+bias, acc[i][1]+bias,
                                      acc[i][2]+bias, acc[i][3]+bias);
        const float4 s1 = make_float4(acc[i][4]+bias, acc[i][5]+bias,
                                      acc[i][6]+bias, acc[i][7]+bias);
        *(float4*)(Yrow + tx*4)      = s0;
        *(float4*)(Yrow + tx*4 + 64) = s1;
    }
}

// ---------------------------------------------------------------------------
// Fused flash-style attention + output:
//   out[b,c,n] = alpha * ( sum_m v[c,m] * softmax_m(q[:,n].k[:,m]) ) + x[b,c,n]
// One block = one (batch, 32-query tile). 256 threads (4 waves).
// Loop over 16 key/value tiles of TM=64 columns with online softmax.
// LDS: q 8K + k 16K + P 8.5K + v-chunk 17K + state = 51 KB -> 3 blocks/CU.
// ---------------------------------------------------------------------------
__global__ __launch_bounds__(256) void attn_kernel(
    const float* __restrict__ qk,   // [B][128][N]: rows 0..63 = q, 64..127 = k
    const float* __restrict__ v,    // [B][512][N]
    const float* __restrict__ x,    // [B][512][N]
    const float* __restrict__ alpha_p,
    float* __restrict__ out)        // [B][512][N]
{
    __shared__ __align__(16) float q_s[64][32];   // [c][nq]
    __shared__ __align__(16) float k_s[64][64];   // [c][m]
    __shared__ __align__(16) float P_s[32][68];   // [nq][m], holds S then P
    __shared__ __align__(16) float v_s[64][68];   // [c_chunk][m]
    __shared__ float row_m[32];
    __shared__ float row_l[32];
    __shared__ float row_scale[32];

    // XCD-contiguous remap: 1024 blocks % 8 == 0 -> bijective.
    const int id  = blockIdx.x;
    const int lin = (id & 7) * 128 + (id >> 3);
    const int b   = lin >> 5;
    const int n0  = (lin & 31) * 32;

    const int t  = threadIdx.x;
    const float* qb = qk + (size_t)b * 128 * N_DIM;
    const float* kb = qb + 64 * N_DIM;
    const float* vb = v  + (size_t)b * C_DIM * N_DIM;

    if (t < 32) { row_m[t] = -INFINITY; row_l[t] = 0.0f; }

    // load Q tile [64][32]
    #pragma unroll
    for (int p = 0; p < 2; ++p) {
        const int c = (t >> 3) + 32 * p;
        *(float4*)&q_s[c][(t & 7) * 4] =
            *(const float4*)&qb[(size_t)c * N_DIM + n0 + (t & 7) * 4];
    }

    float acc[8][2][4];   // [c-chunk][ci][j] ; c = ch*64 + g8 + 32*ci, nq = e8 + 8*j
    #pragma unroll
    for (int ch = 0; ch < 8; ++ch)
        #pragma unroll
        for (int ci = 0; ci < 2; ++ci)
            #pragma unroll
            for (int j = 0; j < 4; ++j) acc[ch][ci][j] = 0.0f;

    const int lm = t & 63;          // step-A key column
    const int wq = (t >> 6) * 8;    // step-A query-row base (per-wave uniform)
    const int e8 = t & 7;           // step-B / epilogue nq base
    const int g8 = t >> 3;          // step-B c base (0..31)

    __syncthreads();

    #pragma unroll 1
    for (int m0 = 0; m0 < N_DIM; m0 += 64) {
        // ---- K tile [64][64]
        #pragma unroll
        for (int p = 0; p < 4; ++p) {
            const int r = (t >> 4) + 16 * p;
            *(float4*)&k_s[r][(t & 15) * 4] =
                *(const float4*)&kb[(size_t)r * N_DIM + m0 + (t & 15) * 4];
        }
        __syncthreads();

        // ---- step A: S[nq][m] = sum_c q[c][nq] * k[c][m]
        float sv[8] = {0.f,0.f,0.f,0.f,0.f,0.f,0.f,0.f};
        #pragma unroll 8
        for (int c = 0; c < 64; ++c) {
            const float kc  = k_s[c][lm];
            const float4 qa = *(const float4*)&q_s[c][wq];
            const float4 qc = *(const float4*)&q_s[c][wq + 4];
            sv[0] = fmaf(kc, qa.x, sv[0]);
            sv[1] = fmaf(kc, qa.y, sv[1]);
            sv[2] = fmaf(kc, qa.z, sv[2]);
            sv[3] = fmaf(kc, qa.w, sv[3]);
            sv[4] = fmaf(kc, qc.x, sv[4]);
            sv[5] = fmaf(kc, qc.y, sv[5]);
            sv[6] = fmaf(kc, qc.z, sv[6]);
            sv[7] = fmaf(kc, qc.w, sv[7]);
        }
        #pragma unroll
        for (int i = 0; i < 8; ++i) P_s[wq + i][lm] = sv[i];
        __syncthreads();

        // ---- online softmax: 8 threads per row, shfl_xor reduce
        {
            const int row = t >> 3, seg = t & 7;
            const float4 sa = *(const float4*)&P_s[row][seg*8];
            const float4 sb = *(const float4*)&P_s[row][seg*8 + 4];
            float mx = fmaxf(fmaxf(fmaxf(sa.x,sa.y), fmaxf(sa.z,sa.w)),
                             fmaxf(fmaxf(sb.x,sb.y), fmaxf(sb.z,sb.w)));
            mx = fmaxf(mx, __shfl_xor(mx, 1));
            mx = fmaxf(mx, __shfl_xor(mx, 2));
            mx = fmaxf(mx, __shfl_xor(mx, 4));
            const float m_old = row_m[row];
            const float m_new = fmaxf(m_old, mx);
            const float p0 = exp2f((sa.x - m_new) * LOG2E);
            const float p1 = exp2f((sa.y - m_new) * LOG2E);
            const float p2 = exp2f((sa.z - m_new) * LOG2E);
            const float p3 = exp2f((sa.w - m_new) * LOG2E);
            const float p4 = exp2f((sb.x - m_new) * LOG2E);
            const float p5 = exp2f((sb.y - m_new) * LOG2E);
            const float p6 = exp2f((sb.z - m_new) * LOG2E);
            const float p7 = exp2f((sb.w - m_new) * LOG2E);
            float sum = ((p0+p1)+(p2+p3)) + ((p4+p5)+(p6+p7));
            sum += __shfl_xor(sum, 1);
            sum += __shfl_xor(sum, 2);
            sum += __shfl_xor(sum, 4);
            *(float4*)&P_s[row][seg*8]     = make_float4(p0,p1,p2,p3);
            *(float4*)&P_s[row][seg*8 + 4] = make_float4(p4,p5,p6,p7);
            if (seg == 0) {
                const float sc = exp2f((m_old - m_new) * LOG2E);
                row_scale[row] = sc;
                row_l[row] = row_l[row] * sc + sum;
                row_m[row] = m_new;
            }
        }
        __syncthreads();

        // ---- rescale accumulators
        {
            float fsc[4];
            #pragma unroll
            for (int j = 0; j < 4; ++j) fsc[j] = row_scale[e8 + 8*j];
            #pragma unroll
            for (int ch = 0; ch < 8; ++ch)
                #pragma unroll
                for (int ci = 0; ci < 2; ++ci)
                    #pragma unroll
                    for (int j = 0; j < 4; ++j)
                        acc[ch][ci][j] *= fsc[j];
        }

        // ---- step B: acc[c][nq] += sum_m v[c][m] * P[nq][m], 64-channel chunks
        #pragma unroll
        for (int ch = 0; ch < 8; ++ch) {
            #pragma unroll
            for (int p = 0; p < 4; ++p) {
                const int r = (t >> 4) + 16 * p;
                *(float4*)&v_s[r][(t & 15) * 4] =
                    *(const float4*)&vb[(size_t)(ch*64 + r) * N_DIM + m0 + (t & 15) * 4];
            }
            __syncthreads();
            #pragma unroll 4
            for (int m4 = 0; m4 < 16; ++m4) {
                const float4 vv0 = *(const float4*)&v_s[g8][m4*4];
                const float4 vv1 = *(const float4*)&v_s[g8 + 32][m4*4];
                float4 pp[4];
                #pragma unroll
                for (int j = 0; j < 4; ++j)
                    pp[j] = *(const float4*)&P_s[e8 + 8*j][m4*4];
                #pragma unroll
                for (int j = 0; j < 4; ++j) {
                    acc[ch][0][j] = fmaf(vv0.x, pp[j].x, acc[ch][0][j]);
                    acc[ch][0][j] = fmaf(vv0.y, pp[j].y, acc[ch][0][j]);
                    acc[ch][0][j] = fmaf(vv0.z, pp[j].z, acc[ch][0][j]);
                    acc[ch][0][j] = fmaf(vv0.w, pp[j].w, acc[ch][0][j]);
                    acc[ch][1][j] = fmaf(vv1.x, pp[j].x, acc[ch][1][j]);
                    acc[ch][1][j] = fmaf(vv1.y, pp[j].y, acc[ch][1][j]);
                    acc[ch][1][j] = fmaf(vv1.z, pp[j].z, acc[ch][1][j]);
                    acc[ch][1][j] = fmaf(vv1.w, pp[j].w, acc[ch][1][j]);
                }
            }
            __syncthreads();
        }
    }

    // ---- epilogue: out = alpha * acc / l + x
    const float alpha = alpha_p[0];
    float inv[4];
    #pragma unroll
    for (int j = 0; j < 4; ++j) inv[j] = alpha / row_l[e8 + 8*j];
    #pragma unroll
    for (int ch = 0; ch < 8; ++ch)
        #pragma unroll
        for (int ci = 0; ci < 2; ++ci) {
            const int c = ch*64 + g8 + 32*ci;
            const size_t base = ((size_t)b * C_DIM + c) * N_DIM + n0;
            #pragma unroll
            for (int j = 0; j < 4; ++j) {
                const int n = e8 + 8*j;
                out[base + n] = fmaf(acc[ch][ci][j], inv[j], x[base + n]);
            }
        }
}

// ---------------------------------------------------------------------------
// Inputs (setup_inputs order): x, Wq, bq, Wk, bk, Wv, bv, alpha (all fp32)
// Workspace: qk [32][128][1024] (16 MB) + v [32][512][1024] (64 MB) = 80 MB
// ---------------------------------------------------------------------------
extern "C" void kernel_launch(void* const* d_in, const int* in_sizes, int n_in,
                              void* d_out, int out_size, void* d_ws, size_t ws_size,
                              hipStream_t stream)
{
    const float* x     = (const float*)d_in[0];
    const float* Wq    = (const float*)d_in[1];
    const float* bq    = (const float*)d_in[2];
    const float* Wk    = (const float*)d_in[3];
    const float* bk    = (const float*)d_in[4];
    const float* Wv    = (const float*)d_in[5];
    const float* bv    = (const float*)d_in[6];
    const float* alpha = (const float*)d_in[7];
    float* out = (float*)d_out;

    float* qk_ws = (float*)d_ws;                              // [32][128][1024]
    float* v_ws  = qk_ws + (size_t)B_DIM * 128 * N_DIM;       // [32][512][1024]

    // q,k projections (stacked into one buffer) and v projection
    proj_kernel<true ><<<dim3(N_DIM/128, 1, B_DIM), 256, 0, stream>>>(x, Wq, bq, Wk, bk, qk_ws);
    proj_kernel<false><<<dim3(N_DIM/128, C_DIM/128, B_DIM), 256, 0, stream>>>(x, Wv, bv, Wv, bv, v_ws);

    // fused attention + residual
    attn_kernel<<<dim3(B_DIM * 32), 256, 0, stream>>>(qk_ws, v_ws, x, alpha, out);
}

// Round 5
// 606.379 us; speedup vs baseline: 2.1292x; 2.1292x over previous
//
#include <hip/hip_runtime.h>
#include <math.h>

#define B_DIM  32
#define C_DIM  512
#define N_DIM  1024
#define LOG2E  1.44269504088896340736f
#define NEG_BIG (-1.0e30f)

typedef __attribute__((ext_vector_type(8))) __bf16 bf16x8;
typedef __attribute__((ext_vector_type(8))) short short8v;
typedef __attribute__((ext_vector_type(4))) short short4v;
typedef __attribute__((ext_vector_type(4))) float floatx4;

__device__ __forceinline__ unsigned short f2bf(float f) {      // RNE fp32->bf16
    unsigned u = __float_as_uint(f);
    return (unsigned short)((u + 0x7FFFu + ((u >> 16) & 1u)) >> 16);
}
__device__ __forceinline__ float bf2f(unsigned short h) {
    return __uint_as_float(((unsigned)h) << 16);
}
__device__ __forceinline__ floatx4 mfma16(short8v a, short8v b, floatx4 c) {
    return __builtin_amdgcn_mfma_f32_16x16x32_bf16(
        __builtin_bit_cast(bf16x8, a), __builtin_bit_cast(bf16x8, b), c, 0, 0, 0);
}
// non-finite -> 0 (diagnostic guard: output always finite, absmax stays readable)
__device__ __forceinline__ float fin(float v) {
    return (__builtin_fabsf(v) <= 1.0e30f) ? v : 0.0f;
}

// ---------------------------------------------------------------------------
// Q,K projection (fp32 VALU, proven R1): Y[b][o][n], o 0..63=q, 64..127=k
// ---------------------------------------------------------------------------
__global__ __launch_bounds__(256) void proj_kernel(
    const float* __restrict__ X,
    const float* __restrict__ Wa, const float* __restrict__ ba,
    const float* __restrict__ Wb, const float* __restrict__ bb,
    float* __restrict__ Y)
{
    __shared__ __align__(16) float As[16][132];
    __shared__ __align__(16) float Bs[16][128];

    const int b  = blockIdx.z;
    const int n0 = blockIdx.x * 128;
    const int t  = threadIdx.x;
    const int tx = t & 15;
    const int ty = t >> 4;

    const float* Xb = X + (size_t)b * C_DIM * N_DIM;

    float acc[8][8];
    #pragma unroll
    for (int i = 0; i < 8; ++i)
        #pragma unroll
        for (int j = 0; j < 8; ++j) acc[i][j] = 0.0f;

    const int ai = t >> 2, ak = t & 3, lk = t >> 5, ln = t & 31;

    for (int k0 = 0; k0 < C_DIM; k0 += 16) {
        #pragma unroll
        for (int p = 0; p < 2; ++p) {
            const int i = ai + 64 * p;
            const float* Wrow = (p == 0) ? (Wa + (size_t)i * C_DIM)
                                         : (Wb + (size_t)(i - 64) * C_DIM);
            const float4 av = *(const float4*)(Wrow + k0 + ak * 4);
            As[ak*4+0][i] = av.x;  As[ak*4+1][i] = av.y;
            As[ak*4+2][i] = av.z;  As[ak*4+3][i] = av.w;
        }
        #pragma unroll
        for (int p = 0; p < 2; ++p) {
            const int k = lk + 8 * p;
            *(float4*)&Bs[k][ln*4] =
                *(const float4*)&Xb[(size_t)(k0 + k) * N_DIM + n0 + ln*4];
        }
        __syncthreads();
        #pragma unroll
        for (int k = 0; k < 16; ++k) {
            const float4 a0 = *(const float4*)&As[k][ty*4];
            const float4 a1 = *(const float4*)&As[k][ty*4 + 64];
            const float4 b0 = *(const float4*)&Bs[k][tx*4];
            const float4 b1 = *(const float4*)&Bs[k][tx*4 + 64];
            const float av[8] = {a0.x,a0.y,a0.z,a0.w,a1.x,a1.y,a1.z,a1.w};
            const float bv[8] = {b0.x,b0.y,b0.z,b0.w,b1.x,b1.y,b1.z,b1.w};
            #pragma unroll
            for (int i = 0; i < 8; ++i)
                #pragma unroll
                for (int j = 0; j < 8; ++j)
                    acc[i][j] = fmaf(av[i], bv[j], acc[i][j]);
        }
        __syncthreads();
    }
    #pragma unroll
    for (int i = 0; i < 8; ++i) {
        const int o = ty*4 + (i & 3) + (i >> 2) * 64;
        const float bias = (i < 4) ? ba[o] : bb[o - 64];
        float* Yrow = Y + ((size_t)b * 128 + o) * N_DIM + n0;
        *(float4*)(Yrow + tx*4)      = make_float4(acc[i][0]+bias, acc[i][1]+bias,
                                                   acc[i][2]+bias, acc[i][3]+bias);
        *(float4*)(Yrow + tx*4 + 64) = make_float4(acc[i][4]+bias, acc[i][5]+bias,
                                                   acc[i][6]+bias, acc[i][7]+bias);
    }
}

// ---------------------------------------------------------------------------
// V projection (proven R1 fp32 GEMM; ONLY the store changed to bf16):
//   vbf[b][c][n] = bf16( sum_ch Wv[c][ch]*X[b][ch][n] + bv[c] )
// ---------------------------------------------------------------------------
__global__ __launch_bounds__(256) void projv_kernel(
    const float* __restrict__ X,
    const float* __restrict__ Wv, const float* __restrict__ bvv,
    unsigned short* __restrict__ Y)
{
    __shared__ __align__(16) float As[16][132];
    __shared__ __align__(16) float Bs[16][128];

    const int b  = blockIdx.z;
    const int o0 = blockIdx.y * 128;
    const int n0 = blockIdx.x * 128;
    const int t  = threadIdx.x;
    const int tx = t & 15;
    const int ty = t >> 4;

    const float* Xb = X + (size_t)b * C_DIM * N_DIM;

    float acc[8][8];
    #pragma unroll
    for (int i = 0; i < 8; ++i)
        #pragma unroll
        for (int j = 0; j < 8; ++j) acc[i][j] = 0.0f;

    const int ai = t >> 2, ak = t & 3, lk = t >> 5, ln = t & 31;

    for (int k0 = 0; k0 < C_DIM; k0 += 16) {
        #pragma unroll
        for (int p = 0; p < 2; ++p) {
            const int i = ai + 64 * p;
            const float* Wrow = Wv + (size_t)(o0 + i) * C_DIM;
            const float4 av = *(const float4*)(Wrow + k0 + ak * 4);
            As[ak*4+0][i] = av.x;  As[ak*4+1][i] = av.y;
            As[ak*4+2][i] = av.z;  As[ak*4+3][i] = av.w;
        }
        #pragma unroll
        for (int p = 0; p < 2; ++p) {
            const int k = lk + 8 * p;
            *(float4*)&Bs[k][ln*4] =
                *(const float4*)&Xb[(size_t)(k0 + k) * N_DIM + n0 + ln*4];
        }
        __syncthreads();
        #pragma unroll
        for (int k = 0; k < 16; ++k) {
            const float4 a0 = *(const float4*)&As[k][ty*4];
            const float4 a1 = *(const float4*)&As[k][ty*4 + 64];
            const float4 b0 = *(const float4*)&Bs[k][tx*4];
            const float4 b1 = *(const float4*)&Bs[k][tx*4 + 64];
            const float av[8] = {a0.x,a0.y,a0.z,a0.w,a1.x,a1.y,a1.z,a1.w};
            const float bv[8] = {b0.x,b0.y,b0.z,b0.w,b1.x,b1.y,b1.z,b1.w};
            #pragma unroll
            for (int i = 0; i < 8; ++i)
                #pragma unroll
                for (int j = 0; j < 8; ++j)
                    acc[i][j] = fmaf(av[i], bv[j], acc[i][j]);
        }
        __syncthreads();
    }
    #pragma unroll
    for (int i = 0; i < 8; ++i) {
        const int o = o0 + ty*4 + (i & 3) + (i >> 2) * 64;
        const float bias = bvv[o];
        unsigned short* Yrow = Y + ((size_t)b * C_DIM + o) * N_DIM + n0;
        short4v s0, s1;
        #pragma unroll
        for (int j = 0; j < 4; ++j) {
            s0[j] = (short)f2bf(acc[i][j]     + bias);
            s1[j] = (short)f2bf(acc[i][j + 4] + bias);
        }
        *(short4v*)(Yrow + tx*4)      = s0;
        *(short4v*)(Yrow + tx*4 + 64) = s1;
    }
}

// ---------------------------------------------------------------------------
// Transpose+split q,k: qk_ws [b][128][1024] fp32 -> qkt [b][4][1024][64] bf16
//   planes: 0=q_hi 1=q_lo 2=k_hi 3=k_lo  (hi+lo = ~fp32-accurate split)
// ---------------------------------------------------------------------------
__global__ __launch_bounds__(256) void tq_kernel(
    const float* __restrict__ qk, unsigned short* __restrict__ qkt)
{
    __shared__ float tile[64][65];
    const int n0 = blockIdx.x * 64, oh = blockIdx.y, b = blockIdx.z;
    const int t = threadIdx.x;

    #pragma unroll
    for (int p = 0; p < 4; ++p) {
        const int r = (t >> 4) + 16 * p;
        const float4 v = *(const float4*)(qk + ((size_t)b*128 + oh*64 + r)*N_DIM
                                          + n0 + (t & 15)*4);
        tile[r][(t&15)*4+0] = v.x;  tile[r][(t&15)*4+1] = v.y;
        tile[r][(t&15)*4+2] = v.z;  tile[r][(t&15)*4+3] = v.w;
    }
    __syncthreads();
    #pragma unroll
    for (int p = 0; p < 2; ++p) {
        const int rn = (t >> 3) + 32 * p;     // output n-row (0..63)
        const int c8 = (t & 7) * 8;           // output c chunk
        short8v hi, lo;
        #pragma unroll
        for (int j = 0; j < 8; ++j) {
            const float f = tile[c8 + j][rn];
            const unsigned short h = f2bf(f);
            hi[j] = (short)h;
            lo[j] = (short)f2bf(f - bf2f(h));
        }
        const size_t base = (((size_t)b*4 + oh*2)*N_DIM + n0 + rn)*64 + c8;
        *(short8v*)(qkt + base)                    = hi;
        *(short8v*)(qkt + base + (size_t)N_DIM*64) = lo;   // next plane
    }
}

// ---------------------------------------------------------------------------
// Fused attention: energy split-bf16 MFMA, online softmax, PV bf16 MFMA
// with V fragments straight from global [c][m].
// FIX (R5): Q/K LDS staging now covers the FULL [rows][64] tiles.
//   (R3/R4 used ch&3 -> only cols 0..31 written; cols 32..63 were
//    uninitialized LDS -> garbage/NaN fragments -> NaN output.)
// ---------------------------------------------------------------------------
__global__ __launch_bounds__(256) void attn_mfma(
    const unsigned short* __restrict__ qkt,  // [b][4][1024][64]
    const unsigned short* __restrict__ vbf,  // [b][512][1024]
    const float* __restrict__ x,
    const float* __restrict__ alpha_p,
    float* __restrict__ out)
{
    __shared__ unsigned short Qh[32][72], Ql[32][72];
    __shared__ unsigned short Kh[64][72], Kl[64][72];
    __shared__ __align__(16) float S[32][68];
    __shared__ unsigned short Pb[32][72];
    __shared__ float row_m[32], row_l[32], row_scale[32];

    const int id  = blockIdx.x;
    const int lin = (id & 7) * 128 + (id >> 3);   // XCD-contiguous (1024%8==0)
    const int b   = lin >> 5;
    const int n0  = (lin & 31) * 32;

    const int t = threadIdx.x, w = t >> 6, l = t & 63;
    const int la = l & 15, lb = l >> 4;
    const unsigned short* qkb = qkt + (size_t)b * 4 * N_DIM * 64;

    // ---- Q tile (both planes) -> LDS. Full coverage: 2 planes x 256 loads.
    #pragma unroll
    for (int plane = 0; plane < 2; ++plane) {
        const int row = t >> 3;                // 0..31
        const int ch  = t & 7;                 // 0..7  (8 shorts each)
        const short8v g = *(const short8v*)(qkb + ((size_t)plane*N_DIM + n0 + row)*64 + ch*8);
        if (plane == 0) *(short8v*)&Qh[row][ch*8] = g;
        else            *(short8v*)&Ql[row][ch*8] = g;
    }
    if (t < 32) { row_m[t] = NEG_BIG; row_l[t] = 0.0f; row_scale[t] = 1.0f; }
    __syncthreads();

    floatx4 acc[2][8];   // [ntile][ctile]; n = nt*16+lb*4+r, c = w*128+ct*16+la
    #pragma unroll
    for (int i = 0; i < 2; ++i)
        #pragma unroll
        for (int j = 0; j < 8; ++j) acc[i][j] = (floatx4)0.0f;

    #pragma unroll 1
    for (int m0 = 0; m0 < N_DIM; m0 += 64) {
        // ---- stage Kt hi/lo [64][64]. Full coverage: 2 planes x 512 loads.
        #pragma unroll
        for (int pp = 0; pp < 4; ++pp) {
            const int plane = pp >> 1;
            const int idx   = t + 256 * (pp & 1);   // 0..511 per plane
            const int row   = idx >> 3;             // 0..63
            const int ch    = idx & 7;              // 0..7
            const short8v g = *(const short8v*)(qkb + ((size_t)(2 + plane)*N_DIM + m0 + row)*64 + ch*8);
            if (plane == 0) *(short8v*)&Kh[row][ch*8] = g;
            else            *(short8v*)&Kl[row][ch*8] = g;
        }
        __syncthreads();

        // ---- energy MFMA: wave w owns m-subtile w; split-bf16 3 terms
        {
            floatx4 e[2] = { (floatx4)0.0f, (floatx4)0.0f };
            #pragma unroll
            for (int ks = 0; ks < 2; ++ks) {
                const short8v ah = *(const short8v*)&Kh[w*16 + la][ks*32 + lb*8];
                const short8v al = *(const short8v*)&Kl[w*16 + la][ks*32 + lb*8];
                #pragma unroll
                for (int nt = 0; nt < 2; ++nt) {
                    const short8v bh = *(const short8v*)&Qh[nt*16 + la][ks*32 + lb*8];
                    const short8v bl = *(const short8v*)&Ql[nt*16 + la][ks*32 + lb*8];
                    e[nt] = mfma16(ah, bh, e[nt]);
                    e[nt] = mfma16(ah, bl, e[nt]);
                    e[nt] = mfma16(al, bh, e[nt]);
                }
            }
            #pragma unroll
            for (int nt = 0; nt < 2; ++nt) {   // D[m][n] -> S[n][m]
                floatx4 ev = e[nt];
                #pragma unroll
                for (int r = 0; r < 4; ++r) ev[r] = fin(ev[r]);
                *(floatx4*)&S[nt*16 + la][w*16 + lb*4] = ev;
            }
        }
        __syncthreads();

        // ---- online softmax (R1-proven structure), emit P as bf16
        {
            const int row = t >> 3, seg = t & 7;
            const float4 sa = *(const float4*)&S[row][seg*8];
            const float4 sb = *(const float4*)&S[row][seg*8 + 4];
            float mx = fmaxf(fmaxf(fmaxf(sa.x,sa.y), fmaxf(sa.z,sa.w)),
                             fmaxf(fmaxf(sb.x,sb.y), fmaxf(sb.z,sb.w)));
            mx = fmaxf(mx, __shfl_xor(mx, 1));
            mx = fmaxf(mx, __shfl_xor(mx, 2));
            mx = fmaxf(mx, __shfl_xor(mx, 4));
            const float m_old = row_m[row];
            const float m_new = fmaxf(m_old, mx);
            const float p0 = exp2f((sa.x - m_new) * LOG2E);
            const float p1 = exp2f((sa.y - m_new) * LOG2E);
            const float p2 = exp2f((sa.z - m_new) * LOG2E);
            const float p3 = exp2f((sa.w - m_new) * LOG2E);
            const float p4 = exp2f((sb.x - m_new) * LOG2E);
            const float p5 = exp2f((sb.y - m_new) * LOG2E);
            const float p6 = exp2f((sb.z - m_new) * LOG2E);
            const float p7 = exp2f((sb.w - m_new) * LOG2E);
            float sum = ((p0+p1)+(p2+p3)) + ((p4+p5)+(p6+p7));
            sum += __shfl_xor(sum, 1);
            sum += __shfl_xor(sum, 2);
            sum += __shfl_xor(sum, 4);
            short8v pk;
            pk[0]=(short)f2bf(p0); pk[1]=(short)f2bf(p1);
            pk[2]=(short)f2bf(p2); pk[3]=(short)f2bf(p3);
            pk[4]=(short)f2bf(p4); pk[5]=(short)f2bf(p5);
            pk[6]=(short)f2bf(p6); pk[7]=(short)f2bf(p7);
            *(short8v*)&Pb[row][seg*8] = pk;
            if (seg == 0) {
                const float sc = exp2f((m_old - m_new) * LOG2E);
                row_scale[row] = sc;
                row_l[row] = row_l[row] * sc + sum;
                row_m[row] = m_new;
            }
        }
        __syncthreads();

        // ---- rescale accumulators (per output row n)
        {
            float fsc[2][4];
            #pragma unroll
            for (int nt = 0; nt < 2; ++nt)
                #pragma unroll
                for (int r = 0; r < 4; ++r) fsc[nt][r] = row_scale[nt*16 + lb*4 + r];
            #pragma unroll
            for (int nt = 0; nt < 2; ++nt)
                #pragma unroll
                for (int ct = 0; ct < 8; ++ct)
                    #pragma unroll
                    for (int r = 0; r < 4; ++r) acc[nt][ct][r] *= fsc[nt][r];
        }

        // ---- PV MFMA: wave w owns c-range w*128..+128; V fragments from global
        #pragma unroll
        for (int ks = 0; ks < 2; ++ks) {
            short8v pa[2];
            #pragma unroll
            for (int nt = 0; nt < 2; ++nt)
                pa[nt] = *(const short8v*)&Pb[nt*16 + la][ks*32 + lb*8];
            const unsigned short* vp =
                vbf + ((size_t)b*C_DIM + w*128 + la)*N_DIM + m0 + ks*32 + lb*8;
            #pragma unroll
            for (int ct = 0; ct < 8; ++ct) {
                const short8v bv8 = *(const short8v*)(vp + (size_t)ct*16*N_DIM);
                acc[0][ct] = mfma16(pa[0], bv8, acc[0][ct]);
                acc[1][ct] = mfma16(pa[1], bv8, acc[1][ct]);
            }
        }
        __syncthreads();
    }

    // ---- epilogue: out = alpha*acc/l + x (sanitized; output always finite)
    const float alpha = alpha_p[0];
    float invl[2][4];
    #pragma unroll
    for (int nt = 0; nt < 2; ++nt)
        #pragma unroll
        for (int r = 0; r < 4; ++r)
            invl[nt][r] = alpha / fmaxf(row_l[nt*16 + lb*4 + r], 1.0e-20f);
    #pragma unroll
    for (int nt = 0; nt < 2; ++nt)
        #pragma unroll
        for (int ct = 0; ct < 8; ++ct) {
            const int c = w*128 + ct*16 + la;
            const size_t base = ((size_t)b*C_DIM + c)*N_DIM + n0 + nt*16 + lb*4;
            const float4 xa = *(const float4*)&x[base];
            float4 o;
            o.x = fmaf(fin(acc[nt][ct][0]), invl[nt][0], xa.x);
            o.y = fmaf(fin(acc[nt][ct][1]), invl[nt][1], xa.y);
            o.z = fmaf(fin(acc[nt][ct][2]), invl[nt][2], xa.z);
            o.w = fmaf(fin(acc[nt][ct][3]), invl[nt][3], xa.w);
            *(float4*)&out[base] = o;
        }
}

// ---------------------------------------------------------------------------
// Workspace (64 MB, < proven 80 MB):
//   [ 0:16MB) qk_ws fp32 [b][128][1024]
//   [16:32MB) qkt  bf16 [b][4][1024][64]
//   [32:64MB) vbf  bf16 [b][512][1024]
// ---------------------------------------------------------------------------
extern "C" void kernel_launch(void* const* d_in, const int* in_sizes, int n_in,
                              void* d_out, int out_size, void* d_ws, size_t ws_size,
                              hipStream_t stream)
{
    const float* x     = (const float*)d_in[0];
    const float* Wq    = (const float*)d_in[1];
    const float* bq    = (const float*)d_in[2];
    const float* Wk    = (const float*)d_in[3];
    const float* bk    = (const float*)d_in[4];
    const float* Wv    = (const float*)d_in[5];
    const float* bv    = (const float*)d_in[6];
    const float* alpha = (const float*)d_in[7];
    float* out = (float*)d_out;

    float*          qk_ws = (float*)d_ws;
    unsigned short* qkt   = (unsigned short*)((char*)d_ws + (size_t)16*1024*1024);
    unsigned short* vbf   = (unsigned short*)((char*)d_ws + (size_t)32*1024*1024);

    proj_kernel<<<dim3(N_DIM/128, 1, B_DIM), 256, 0, stream>>>(x, Wq, bq, Wk, bk, qk_ws);
    tq_kernel<<<dim3(16, 2, B_DIM), 256, 0, stream>>>(qk_ws, qkt);
    projv_kernel<<<dim3(N_DIM/128, C_DIM/128, B_DIM), 256, 0, stream>>>(x, Wv, bv, vbf);
    attn_mfma<<<dim3(B_DIM * 32), 256, 0, stream>>>(qkt, vbf, x, alpha, out);
}

// Round 6
// 444.779 us; speedup vs baseline: 2.9028x; 1.3633x over previous
//
#include <hip/hip_runtime.h>
#include <math.h>

#define B_DIM  32
#define C_DIM  512
#define N_DIM  1024
#define LOG2E  1.44269504088896340736f
#define NEG_BIG (-1.0e30f)

typedef __attribute__((ext_vector_type(8))) __bf16 bf16x8;
typedef __attribute__((ext_vector_type(8))) short short8v;
typedef __attribute__((ext_vector_type(4))) short short4v;
typedef __attribute__((ext_vector_type(4))) float floatx4;

__device__ __forceinline__ unsigned short f2bf(float f) {      // RNE fp32->bf16
    unsigned u = __float_as_uint(f);
    return (unsigned short)((u + 0x7FFFu + ((u >> 16) & 1u)) >> 16);
}
__device__ __forceinline__ float bf2f(unsigned short h) {
    return __uint_as_float(((unsigned)h) << 16);
}
__device__ __forceinline__ floatx4 mfma16(short8v a, short8v b, floatx4 c) {
    return __builtin_amdgcn_mfma_f32_16x16x32_bf16(
        __builtin_bit_cast(bf16x8, a), __builtin_bit_cast(bf16x8, b), c, 0, 0, 0);
}
// non-finite -> 0 (diagnostic guard: output always finite, absmax stays readable)
__device__ __forceinline__ float fin(float v) {
    return (__builtin_fabsf(v) <= 1.0e30f) ? v : 0.0f;
}

// ---------------------------------------------------------------------------
// Transpose+split x: [b][512][1024] fp32 -> xth/xtl bf16 [b][1024][512]
// (hi + lo planes; hi for V projection, hi+lo for split-accurate q/k proj)
// Coverage: read 4x256x4 fp32 = 64x64; write 2x256x8 shorts per plane = 64x64.
// ---------------------------------------------------------------------------
__global__ __launch_bounds__(256) void tx2_kernel(
    const float* __restrict__ x,
    unsigned short* __restrict__ xth, unsigned short* __restrict__ xtl)
{
    __shared__ float tile[64][65];
    const int n0 = blockIdx.x * 64, c0 = blockIdx.y * 64, b = blockIdx.z;
    const int t = threadIdx.x;

    #pragma unroll
    for (int p = 0; p < 4; ++p) {
        const int r = (t >> 4) + 16 * p;
        const float4 v = *(const float4*)(x + ((size_t)b*C_DIM + c0 + r)*N_DIM
                                          + n0 + (t & 15)*4);
        tile[r][(t&15)*4+0] = v.x;  tile[r][(t&15)*4+1] = v.y;
        tile[r][(t&15)*4+2] = v.z;  tile[r][(t&15)*4+3] = v.w;
    }
    __syncthreads();
    #pragma unroll
    for (int p = 0; p < 2; ++p) {
        const int rn = (t >> 3) + 32 * p;     // output n-row (0..63)
        const int c8 = (t & 7) * 8;           // output c chunk
        short8v hi, lo;
        #pragma unroll
        for (int j = 0; j < 8; ++j) {
            const float f = tile[c8 + j][rn];
            const unsigned short h = f2bf(f);
            hi[j] = (short)h;
            lo[j] = (short)f2bf(f - bf2f(h));
        }
        const size_t base = ((size_t)b*N_DIM + n0 + rn)*C_DIM + c0 + c8;
        *(short8v*)(xth + base) = hi;
        *(short8v*)(xtl + base) = lo;
    }
}

// ---------------------------------------------------------------------------
// Q,K projection via split-bf16 MFMA, writing qkt planes DIRECTLY:
//   D[n][o] = sum_ch X^T[n][ch] * Wqk[o][ch]   (o 0..63=q, 64..127=k)
//   3 terms: Ah*Bh + Ah*Bl + Al*Bh  ->  ~fp32-accurate q/k
// Epilogue adds bias then splits hi/lo into qkt [b][4][1024][64]
// (planes 0=q_hi 1=q_lo 2=k_hi 3=k_lo) — same layout R5's attn validated.
// Wave grid 2x2: nh=(w&1)*64 (n-half), oh=(w>>1)*64 (o-half). acc[4][4].
// ---------------------------------------------------------------------------
__global__ __launch_bounds__(256) void qkproj_mfma(
    const unsigned short* __restrict__ xth, const unsigned short* __restrict__ xtl,
    const float* __restrict__ Wq, const float* __restrict__ bq,
    const float* __restrict__ Wk, const float* __restrict__ bk,
    unsigned short* __restrict__ qkt)
{
    __shared__ unsigned short Ah[128][40], Al[128][40];
    __shared__ unsigned short Bh[128][40], Bl[128][40];
    const int b = blockIdx.z, n0 = blockIdx.x * 128;
    const int t = threadIdx.x, w = t >> 6, l = t & 63;
    const int la = l & 15, lb = l >> 4;
    const int nh = (w & 1) * 64, oh = (w >> 1) * 64;

    floatx4 acc[4][4];
    #pragma unroll
    for (int i = 0; i < 4; ++i)
        #pragma unroll
        for (int j = 0; j < 4; ++j) acc[i][j] = (floatx4)0.0f;

    for (int k0 = 0; k0 < C_DIM; k0 += 32) {
        // A stage (both planes): 2 passes x 256 thr x 8 shorts = 128x32 each
        #pragma unroll
        for (int p = 0; p < 2; ++p) {
            const int idx = t + 256*p, row = idx >> 2, ch = idx & 3;
            const size_t g = ((size_t)b*N_DIM + n0 + row)*C_DIM + k0 + ch*8;
            *(short8v*)&Ah[row][ch*8] = *(const short8v*)(xth + g);
            *(short8v*)&Al[row][ch*8] = *(const short8v*)(xtl + g);
        }
        // B stage: Wq/Wk fp32 -> hi/lo. 4 passes x 256 x float4 = 128x32 floats
        #pragma unroll
        for (int p = 0; p < 4; ++p) {
            const int idx = t + 256*p, row = idx >> 3, ch = idx & 7;
            const float* Wrow = (row < 64) ? (Wq + (size_t)row * C_DIM)
                                           : (Wk + (size_t)(row - 64) * C_DIM);
            const float4 wv = *(const float4*)(Wrow + k0 + ch*4);
            const float fv[4] = {wv.x, wv.y, wv.z, wv.w};
            short4v sh, sl;
            #pragma unroll
            for (int j = 0; j < 4; ++j) {
                const unsigned short h = f2bf(fv[j]);
                sh[j] = (short)h;
                sl[j] = (short)f2bf(fv[j] - bf2f(h));
            }
            *(short4v*)&Bh[row][ch*4] = sh;
            *(short4v*)&Bl[row][ch*4] = sl;
        }
        __syncthreads();

        short8v ahf[4], alf[4], bhf[4], blf[4];
        #pragma unroll
        for (int nt = 0; nt < 4; ++nt) {
            ahf[nt] = *(const short8v*)&Ah[nh + nt*16 + la][lb*8];
            alf[nt] = *(const short8v*)&Al[nh + nt*16 + la][lb*8];
        }
        #pragma unroll
        for (int ot = 0; ot < 4; ++ot) {
            bhf[ot] = *(const short8v*)&Bh[oh + ot*16 + la][lb*8];
            blf[ot] = *(const short8v*)&Bl[oh + ot*16 + la][lb*8];
        }
        #pragma unroll
        for (int nt = 0; nt < 4; ++nt)
            #pragma unroll
            for (int ot = 0; ot < 4; ++ot) {
                acc[nt][ot] = mfma16(ahf[nt], bhf[ot], acc[nt][ot]);
                acc[nt][ot] = mfma16(ahf[nt], blf[ot], acc[nt][ot]);
                acc[nt][ot] = mfma16(alf[nt], bhf[ot], acc[nt][ot]);
            }
        __syncthreads();
    }

    // epilogue: bias, then hi/lo split straight into qkt planes
    const int plane = (oh == 0) ? 0 : 2;     // wave-uniform
    #pragma unroll
    for (int ot = 0; ot < 4; ++ot) {
        const int o = oh + ot*16 + la;       // 0..127 (D col = B row = o)
        const int c = o & 63;
        const float bias = (oh == 0) ? bq[o] : bk[o - 64];
        #pragma unroll
        for (int nt = 0; nt < 4; ++nt)
            #pragma unroll
            for (int r = 0; r < 4; ++r) {
                const int n = n0 + nh + nt*16 + lb*4 + r;   // D row = A row = n
                const float f = acc[nt][ot][r] + bias;
                const unsigned short h = f2bf(f);
                const unsigned short lo16 = f2bf(f - bf2f(h));
                qkt[(((size_t)b*4 + plane    )*N_DIM + n)*64 + c] = h;
                qkt[(((size_t)b*4 + plane + 1)*N_DIM + n)*64 + c] = lo16;
            }
    }
}

// ---------------------------------------------------------------------------
// V projection, bf16 MFMA (R2 structure, staging coverage re-audited):
//   D[m][c] = sum_ch Xt[b][m][ch] * Wv[c][ch] (+bv) -> vbf [b][c][m] bf16
// Output [c][m] (m innermost) is exactly the PV B-fragment layout.
// ---------------------------------------------------------------------------
__global__ __launch_bounds__(256) void vproj_mfma(
    const unsigned short* __restrict__ xt,
    const float* __restrict__ Wv, const float* __restrict__ bvv,
    unsigned short* __restrict__ vbf)
{
    __shared__ unsigned short Axs[128][40];
    __shared__ unsigned short Bws[128][40];
    const int b = blockIdx.z, m0 = blockIdx.x * 128, c0 = blockIdx.y * 128;
    const int t = threadIdx.x, w = t >> 6, l = t & 63;
    const int la = l & 15, lb = l >> 4;
    const int mh = (w & 1) * 64, chh = (w >> 1) * 64;

    floatx4 acc[4][4];
    #pragma unroll
    for (int i = 0; i < 4; ++i)
        #pragma unroll
        for (int j = 0; j < 4; ++j) acc[i][j] = (floatx4)0.0f;

    for (int k0 = 0; k0 < C_DIM; k0 += 32) {
        #pragma unroll
        for (int p = 0; p < 2; ++p) {            // A: 2x256x8 = 128x32 shorts
            const int idx = t + 256 * p;
            const int row = idx >> 2, ch = idx & 3;
            *(short8v*)&Axs[row][ch*8] =
                *(const short8v*)(xt + ((size_t)b*N_DIM + m0 + row)*C_DIM + k0 + ch*8);
        }
        #pragma unroll
        for (int p = 0; p < 4; ++p) {            // B: 4x256 float4 = 128x32 floats
            const int idx = t + 256 * p;
            const int row = idx >> 3, ch = idx & 7;
            const float4 wv = *(const float4*)(Wv + (size_t)(c0 + row)*C_DIM + k0 + ch*4);
            short4v s;
            s[0] = (short)f2bf(wv.x); s[1] = (short)f2bf(wv.y);
            s[2] = (short)f2bf(wv.z); s[3] = (short)f2bf(wv.w);
            *(short4v*)&Bws[row][ch*4] = s;
        }
        __syncthreads();
        short8v af[4], bfv[4];
        #pragma unroll
        for (int mt = 0; mt < 4; ++mt)
            af[mt] = *(const short8v*)&Axs[mh + mt*16 + la][lb*8];
        #pragma unroll
        for (int ct = 0; ct < 4; ++ct)
            bfv[ct] = *(const short8v*)&Bws[chh + ct*16 + la][lb*8];
        #pragma unroll
        for (int mt = 0; mt < 4; ++mt)
            #pragma unroll
            for (int ct = 0; ct < 4; ++ct)
                acc[mt][ct] = mfma16(af[mt], bfv[ct], acc[mt][ct]);
        __syncthreads();
    }
    #pragma unroll
    for (int ct = 0; ct < 4; ++ct) {
        const int c = c0 + chh + ct*16 + la;
        const float bias = bvv[c];
        #pragma unroll
        for (int mt = 0; mt < 4; ++mt) {
            const int m = m0 + mh + mt*16 + lb*4;
            short4v s;
            #pragma unroll
            for (int r = 0; r < 4; ++r) s[r] = (short)f2bf(acc[mt][ct][r] + bias);
            *(short4v*)(vbf + ((size_t)b*C_DIM + c)*N_DIM + m) = s;
        }
    }
}

// ---------------------------------------------------------------------------
// Fused attention — BYTE-IDENTICAL to the R5 PASSED kernel.
// energy split-bf16 MFMA, online softmax, PV bf16 MFMA (V frags from global).
// ---------------------------------------------------------------------------
__global__ __launch_bounds__(256) void attn_mfma(
    const unsigned short* __restrict__ qkt,  // [b][4][1024][64]
    const unsigned short* __restrict__ vbf,  // [b][512][1024]
    const float* __restrict__ x,
    const float* __restrict__ alpha_p,
    float* __restrict__ out)
{
    __shared__ unsigned short Qh[32][72], Ql[32][72];
    __shared__ unsigned short Kh[64][72], Kl[64][72];
    __shared__ __align__(16) float S[32][68];
    __shared__ unsigned short Pb[32][72];
    __shared__ float row_m[32], row_l[32], row_scale[32];

    const int id  = blockIdx.x;
    const int lin = (id & 7) * 128 + (id >> 3);   // XCD-contiguous (1024%8==0)
    const int b   = lin >> 5;
    const int n0  = (lin & 31) * 32;

    const int t = threadIdx.x, w = t >> 6, l = t & 63;
    const int la = l & 15, lb = l >> 4;
    const unsigned short* qkb = qkt + (size_t)b * 4 * N_DIM * 64;

    // ---- Q tile (both planes) -> LDS. Full coverage: 2 planes x 256 loads.
    #pragma unroll
    for (int plane = 0; plane < 2; ++plane) {
        const int row = t >> 3;                // 0..31
        const int ch  = t & 7;                 // 0..7  (8 shorts each)
        const short8v g = *(const short8v*)(qkb + ((size_t)plane*N_DIM + n0 + row)*64 + ch*8);
        if (plane == 0) *(short8v*)&Qh[row][ch*8] = g;
        else            *(short8v*)&Ql[row][ch*8] = g;
    }
    if (t < 32) { row_m[t] = NEG_BIG; row_l[t] = 0.0f; row_scale[t] = 1.0f; }
    __syncthreads();

    floatx4 acc[2][8];   // [ntile][ctile]; n = nt*16+lb*4+r, c = w*128+ct*16+la
    #pragma unroll
    for (int i = 0; i < 2; ++i)
        #pragma unroll
        for (int j = 0; j < 8; ++j) acc[i][j] = (floatx4)0.0f;

    #pragma unroll 1
    for (int m0 = 0; m0 < N_DIM; m0 += 64) {
        // ---- stage Kt hi/lo [64][64]. Full coverage: 2 planes x 512 loads.
        #pragma unroll
        for (int pp = 0; pp < 4; ++pp) {
            const int plane = pp >> 1;
            const int idx   = t + 256 * (pp & 1);   // 0..511 per plane
            const int row   = idx >> 3;             // 0..63
            const int ch    = idx & 7;              // 0..7
            const short8v g = *(const short8v*)(qkb + ((size_t)(2 + plane)*N_DIM + m0 + row)*64 + ch*8);
            if (plane == 0) *(short8v*)&Kh[row][ch*8] = g;
            else            *(short8v*)&Kl[row][ch*8] = g;
        }
        __syncthreads();

        // ---- energy MFMA: wave w owns m-subtile w; split-bf16 3 terms
        {
            floatx4 e[2] = { (floatx4)0.0f, (floatx4)0.0f };
            #pragma unroll
            for (int ks = 0; ks < 2; ++ks) {
                const short8v ah = *(const short8v*)&Kh[w*16 + la][ks*32 + lb*8];
                const short8v al = *(const short8v*)&Kl[w*16 + la][ks*32 + lb*8];
                #pragma unroll
                for (int nt = 0; nt < 2; ++nt) {
                    const short8v bh = *(const short8v*)&Qh[nt*16 + la][ks*32 + lb*8];
                    const short8v bl = *(const short8v*)&Ql[nt*16 + la][ks*32 + lb*8];
                    e[nt] = mfma16(ah, bh, e[nt]);
                    e[nt] = mfma16(ah, bl, e[nt]);
                    e[nt] = mfma16(al, bh, e[nt]);
                }
            }
            #pragma unroll
            for (int nt = 0; nt < 2; ++nt) {   // D[m][n] -> S[n][m]
                floatx4 ev = e[nt];
                #pragma unroll
                for (int r = 0; r < 4; ++r) ev[r] = fin(ev[r]);
                *(floatx4*)&S[nt*16 + la][w*16 + lb*4] = ev;
            }
        }
        __syncthreads();

        // ---- online softmax (R1-proven structure), emit P as bf16
        {
            const int row = t >> 3, seg = t & 7;
            const float4 sa = *(const float4*)&S[row][seg*8];
            const float4 sb = *(const float4*)&S[row][seg*8 + 4];
            float mx = fmaxf(fmaxf(fmaxf(sa.x,sa.y), fmaxf(sa.z,sa.w)),
                             fmaxf(fmaxf(sb.x,sb.y), fmaxf(sb.z,sb.w)));
            mx = fmaxf(mx, __shfl_xor(mx, 1));
            mx = fmaxf(mx, __shfl_xor(mx, 2));
            mx = fmaxf(mx, __shfl_xor(mx, 4));
            const float m_old = row_m[row];
            const float m_new = fmaxf(m_old, mx);
            const float p0 = exp2f((sa.x - m_new) * LOG2E);
            const float p1 = exp2f((sa.y - m_new) * LOG2E);
            const float p2 = exp2f((sa.z - m_new) * LOG2E);
            const float p3 = exp2f((sa.w - m_new) * LOG2E);
            const float p4 = exp2f((sb.x - m_new) * LOG2E);
            const float p5 = exp2f((sb.y - m_new) * LOG2E);
            const float p6 = exp2f((sb.z - m_new) * LOG2E);
            const float p7 = exp2f((sb.w - m_new) * LOG2E);
            float sum = ((p0+p1)+(p2+p3)) + ((p4+p5)+(p6+p7));
            sum += __shfl_xor(sum, 1);
            sum += __shfl_xor(sum, 2);
            sum += __shfl_xor(sum, 4);
            short8v pk;
            pk[0]=(short)f2bf(p0); pk[1]=(short)f2bf(p1);
            pk[2]=(short)f2bf(p2); pk[3]=(short)f2bf(p3);
            pk[4]=(short)f2bf(p4); pk[5]=(short)f2bf(p5);
            pk[6]=(short)f2bf(p6); pk[7]=(short)f2bf(p7);
            *(short8v*)&Pb[row][seg*8] = pk;
            if (seg == 0) {
                const float sc = exp2f((m_old - m_new) * LOG2E);
                row_scale[row] = sc;
                row_l[row] = row_l[row] * sc + sum;
                row_m[row] = m_new;
            }
        }
        __syncthreads();

        // ---- rescale accumulators (per output row n)
        {
            float fsc[2][4];
            #pragma unroll
            for (int nt = 0; nt < 2; ++nt)
                #pragma unroll
                for (int r = 0; r < 4; ++r) fsc[nt][r] = row_scale[nt*16 + lb*4 + r];
            #pragma unroll
            for (int nt = 0; nt < 2; ++nt)
                #pragma unroll
                for (int ct = 0; ct < 8; ++ct)
                    #pragma unroll
                    for (int r = 0; r < 4; ++r) acc[nt][ct][r] *= fsc[nt][r];
        }

        // ---- PV MFMA: wave w owns c-range w*128..+128; V fragments from global
        #pragma unroll
        for (int ks = 0; ks < 2; ++ks) {
            short8v pa[2];
            #pragma unroll
            for (int nt = 0; nt < 2; ++nt)
                pa[nt] = *(const short8v*)&Pb[nt*16 + la][ks*32 + lb*8];
            const unsigned short* vp =
                vbf + ((size_t)b*C_DIM + w*128 + la)*N_DIM + m0 + ks*32 + lb*8;
            #pragma unroll
            for (int ct = 0; ct < 8; ++ct) {
                const short8v bv8 = *(const short8v*)(vp + (size_t)ct*16*N_DIM);
                acc[0][ct] = mfma16(pa[0], bv8, acc[0][ct]);
                acc[1][ct] = mfma16(pa[1], bv8, acc[1][ct]);
            }
        }
        __syncthreads();
    }

    // ---- epilogue: out = alpha*acc/l + x (sanitized; output always finite)
    const float alpha = alpha_p[0];
    float invl[2][4];
    #pragma unroll
    for (int nt = 0; nt < 2; ++nt)
        #pragma unroll
        for (int r = 0; r < 4; ++r)
            invl[nt][r] = alpha / fmaxf(row_l[nt*16 + lb*4 + r], 1.0e-20f);
    #pragma unroll
    for (int nt = 0; nt < 2; ++nt)
        #pragma unroll
        for (int ct = 0; ct < 8; ++ct) {
            const int c = w*128 + ct*16 + la;
            const size_t base = ((size_t)b*C_DIM + c)*N_DIM + n0 + nt*16 + lb*4;
            const float4 xa = *(const float4*)&x[base];
            float4 o;
            o.x = fmaf(fin(acc[nt][ct][0]), invl[nt][0], xa.x);
            o.y = fmaf(fin(acc[nt][ct][1]), invl[nt][1], xa.y);
            o.z = fmaf(fin(acc[nt][ct][2]), invl[nt][2], xa.z);
            o.w = fmaf(fin(acc[nt][ct][3]), invl[nt][3], xa.w);
            *(float4*)&out[base] = o;
        }
}

// ---------------------------------------------------------------------------
// Workspace (exactly 80 MiB, the R1-proven footprint):
//   [ 0:32M) xth bf16 [b][1024][512]
//   [32:64M) xtl bf16 [b][1024][512]  -> dead after qkproj; ALIASED by vbf
//   [64:80M) qkt bf16 [b][4][1024][64]
// Order: tx2 -> qkproj (reads xtl) -> vproj (overwrites xtl w/ vbf) -> attn.
// ---------------------------------------------------------------------------
extern "C" void kernel_launch(void* const* d_in, const int* in_sizes, int n_in,
                              void* d_out, int out_size, void* d_ws, size_t ws_size,
                              hipStream_t stream)
{
    const float* x     = (const float*)d_in[0];
    const float* Wq    = (const float*)d_in[1];
    const float* bq    = (const float*)d_in[2];
    const float* Wk    = (const float*)d_in[3];
    const float* bk    = (const float*)d_in[4];
    const float* Wv    = (const float*)d_in[5];
    const float* bv    = (const float*)d_in[6];
    const float* alpha = (const float*)d_in[7];
    float* out = (float*)d_out;

    unsigned short* xth = (unsigned short*)d_ws;
    unsigned short* xtl = (unsigned short*)((char*)d_ws + ((size_t)32 << 20));
    unsigned short* vbf = xtl;   // aliases xtl (dead after qkproj; stream-ordered)
    unsigned short* qkt = (unsigned short*)((char*)d_ws + ((size_t)64 << 20));

    tx2_kernel <<<dim3(16, 8, B_DIM), 256, 0, stream>>>(x, xth, xtl);
    qkproj_mfma<<<dim3(8, 1, B_DIM), 256, 0, stream>>>(xth, xtl, Wq, bq, Wk, bk, qkt);
    vproj_mfma <<<dim3(8, 4, B_DIM), 256, 0, stream>>>(xth, Wv, bv, vbf);
    attn_mfma  <<<dim3(B_DIM * 32), 256, 0, stream>>>(qkt, vbf, x, alpha, out);
}

// Round 7
// 371.011 us; speedup vs baseline: 3.4799x; 1.1988x over previous
//
#include <hip/hip_runtime.h>
#include <math.h>

#define B_DIM  32
#define C_DIM  512
#define N_DIM  1024
#define LOG2E  1.44269504088896340736f
#define NEG_BIG (-1.0e30f)

typedef __attribute__((ext_vector_type(8))) __bf16 bf16x8;
typedef __attribute__((ext_vector_type(8))) short short8v;
typedef __attribute__((ext_vector_type(4))) short short4v;
typedef __attribute__((ext_vector_type(4))) float floatx4;

__device__ __forceinline__ unsigned short f2bf(float f) {      // RNE fp32->bf16
    unsigned u = __float_as_uint(f);
    return (unsigned short)((u + 0x7FFFu + ((u >> 16) & 1u)) >> 16);
}
__device__ __forceinline__ float bf2f(unsigned short h) {
    return __uint_as_float(((unsigned)h) << 16);
}
__device__ __forceinline__ floatx4 mfma16(short8v a, short8v b, floatx4 c) {
    return __builtin_amdgcn_mfma_f32_16x16x32_bf16(
        __builtin_bit_cast(bf16x8, a), __builtin_bit_cast(bf16x8, b), c, 0, 0, 0);
}
// non-finite -> 0 (diagnostic guard: output always finite, absmax stays readable)
__device__ __forceinline__ float fin(float v) {
    return (__builtin_fabsf(v) <= 1.0e30f) ? v : 0.0f;
}

// Raw barrier that does NOT drain vmcnt (unlike __syncthreads, which compiles
// to s_waitcnt vmcnt(0) lgkmcnt(0); s_barrier and kills global-load prefetch).
// Writer-side lgkmcnt(0) drains this wave's LDS writes; "memory" clobbers pin
// compile-time ordering of LDS ops around the barrier.
#define BAR_LDS()  do {                                            \
    asm volatile("s_waitcnt lgkmcnt(0)" ::: "memory");             \
    __builtin_amdgcn_s_barrier();                                  \
    asm volatile("" ::: "memory");                                 \
} while (0)

// ---------------------------------------------------------------------------
// Transpose+split x: [b][512][1024] fp32 -> xth/xtl bf16 [b][1024][512]
// (hi + lo planes; hi for V projection, hi+lo for split-accurate q/k proj)
// ---------------------------------------------------------------------------
__global__ __launch_bounds__(256) void tx2_kernel(
    const float* __restrict__ x,
    unsigned short* __restrict__ xth, unsigned short* __restrict__ xtl)
{
    __shared__ float tile[64][65];
    const int n0 = blockIdx.x * 64, c0 = blockIdx.y * 64, b = blockIdx.z;
    const int t = threadIdx.x;

    #pragma unroll
    for (int p = 0; p < 4; ++p) {
        const int r = (t >> 4) + 16 * p;
        const float4 v = *(const float4*)(x + ((size_t)b*C_DIM + c0 + r)*N_DIM
                                          + n0 + (t & 15)*4);
        tile[r][(t&15)*4+0] = v.x;  tile[r][(t&15)*4+1] = v.y;
        tile[r][(t&15)*4+2] = v.z;  tile[r][(t&15)*4+3] = v.w;
    }
    __syncthreads();
    #pragma unroll
    for (int p = 0; p < 2; ++p) {
        const int rn = (t >> 3) + 32 * p;     // output n-row (0..63)
        const int c8 = (t & 7) * 8;           // output c chunk
        short8v hi, lo;
        #pragma unroll
        for (int j = 0; j < 8; ++j) {
            const float f = tile[c8 + j][rn];
            const unsigned short h = f2bf(f);
            hi[j] = (short)h;
            lo[j] = (short)f2bf(f - bf2f(h));
        }
        const size_t base = ((size_t)b*N_DIM + n0 + rn)*C_DIM + c0 + c8;
        *(short8v*)(xth + base) = hi;
        *(short8v*)(xtl + base) = lo;
    }
}

// ---------------------------------------------------------------------------
// Q,K projection via split-bf16 MFMA, writing qkt planes DIRECTLY (R6-proven).
// ---------------------------------------------------------------------------
__global__ __launch_bounds__(256) void qkproj_mfma(
    const unsigned short* __restrict__ xth, const unsigned short* __restrict__ xtl,
    const float* __restrict__ Wq, const float* __restrict__ bq,
    const float* __restrict__ Wk, const float* __restrict__ bk,
    unsigned short* __restrict__ qkt)
{
    __shared__ unsigned short Ah[128][40], Al[128][40];
    __shared__ unsigned short Bh[128][40], Bl[128][40];
    const int b = blockIdx.z, n0 = blockIdx.x * 128;
    const int t = threadIdx.x, w = t >> 6, l = t & 63;
    const int la = l & 15, lb = l >> 4;
    const int nh = (w & 1) * 64, oh = (w >> 1) * 64;

    floatx4 acc[4][4];
    #pragma unroll
    for (int i = 0; i < 4; ++i)
        #pragma unroll
        for (int j = 0; j < 4; ++j) acc[i][j] = (floatx4)0.0f;

    for (int k0 = 0; k0 < C_DIM; k0 += 32) {
        #pragma unroll
        for (int p = 0; p < 2; ++p) {
            const int idx = t + 256*p, row = idx >> 2, ch = idx & 3;
            const size_t g = ((size_t)b*N_DIM + n0 + row)*C_DIM + k0 + ch*8;
            *(short8v*)&Ah[row][ch*8] = *(const short8v*)(xth + g);
            *(short8v*)&Al[row][ch*8] = *(const short8v*)(xtl + g);
        }
        #pragma unroll
        for (int p = 0; p < 4; ++p) {
            const int idx = t + 256*p, row = idx >> 3, ch = idx & 7;
            const float* Wrow = (row < 64) ? (Wq + (size_t)row * C_DIM)
                                           : (Wk + (size_t)(row - 64) * C_DIM);
            const float4 wv = *(const float4*)(Wrow + k0 + ch*4);
            const float fv[4] = {wv.x, wv.y, wv.z, wv.w};
            short4v sh, sl;
            #pragma unroll
            for (int j = 0; j < 4; ++j) {
                const unsigned short h = f2bf(fv[j]);
                sh[j] = (short)h;
                sl[j] = (short)f2bf(fv[j] - bf2f(h));
            }
            *(short4v*)&Bh[row][ch*4] = sh;
            *(short4v*)&Bl[row][ch*4] = sl;
        }
        __syncthreads();

        short8v ahf[4], alf[4], bhf[4], blf[4];
        #pragma unroll
        for (int nt = 0; nt < 4; ++nt) {
            ahf[nt] = *(const short8v*)&Ah[nh + nt*16 + la][lb*8];
            alf[nt] = *(const short8v*)&Al[nh + nt*16 + la][lb*8];
        }
        #pragma unroll
        for (int ot = 0; ot < 4; ++ot) {
            bhf[ot] = *(const short8v*)&Bh[oh + ot*16 + la][lb*8];
            blf[ot] = *(const short8v*)&Bl[oh + ot*16 + la][lb*8];
        }
        #pragma unroll
        for (int nt = 0; nt < 4; ++nt)
            #pragma unroll
            for (int ot = 0; ot < 4; ++ot) {
                acc[nt][ot] = mfma16(ahf[nt], bhf[ot], acc[nt][ot]);
                acc[nt][ot] = mfma16(ahf[nt], blf[ot], acc[nt][ot]);
                acc[nt][ot] = mfma16(alf[nt], bhf[ot], acc[nt][ot]);
            }
        __syncthreads();
    }

    const int plane = (oh == 0) ? 0 : 2;     // wave-uniform
    #pragma unroll
    for (int ot = 0; ot < 4; ++ot) {
        const int o = oh + ot*16 + la;
        const int c = o & 63;
        const float bias = (oh == 0) ? bq[o] : bk[o - 64];
        #pragma unroll
        for (int nt = 0; nt < 4; ++nt)
            #pragma unroll
            for (int r = 0; r < 4; ++r) {
                const int n = n0 + nh + nt*16 + lb*4 + r;
                const float f = acc[nt][ot][r] + bias;
                const unsigned short h = f2bf(f);
                const unsigned short lo16 = f2bf(f - bf2f(h));
                qkt[(((size_t)b*4 + plane    )*N_DIM + n)*64 + c] = h;
                qkt[(((size_t)b*4 + plane + 1)*N_DIM + n)*64 + c] = lo16;
            }
    }
}

// ---------------------------------------------------------------------------
// V projection, bf16 MFMA (R6-proven): vbf [b][c][m] bf16, m innermost.
// ---------------------------------------------------------------------------
__global__ __launch_bounds__(256) void vproj_mfma(
    const unsigned short* __restrict__ xt,
    const float* __restrict__ Wv, const float* __restrict__ bvv,
    unsigned short* __restrict__ vbf)
{
    __shared__ unsigned short Axs[128][40];
    __shared__ unsigned short Bws[128][40];
    const int b = blockIdx.z, m0 = blockIdx.x * 128, c0 = blockIdx.y * 128;
    const int t = threadIdx.x, w = t >> 6, l = t & 63;
    const int la = l & 15, lb = l >> 4;
    const int mh = (w & 1) * 64, chh = (w >> 1) * 64;

    floatx4 acc[4][4];
    #pragma unroll
    for (int i = 0; i < 4; ++i)
        #pragma unroll
        for (int j = 0; j < 4; ++j) acc[i][j] = (floatx4)0.0f;

    for (int k0 = 0; k0 < C_DIM; k0 += 32) {
        #pragma unroll
        for (int p = 0; p < 2; ++p) {
            const int idx = t + 256 * p;
            const int row = idx >> 2, ch = idx & 3;
            *(short8v*)&Axs[row][ch*8] =
                *(const short8v*)(xt + ((size_t)b*N_DIM + m0 + row)*C_DIM + k0 + ch*8);
        }
        #pragma unroll
        for (int p = 0; p < 4; ++p) {
            const int idx = t + 256 * p;
            const int row = idx >> 3, ch = idx & 7;
            const float4 wv = *(const float4*)(Wv + (size_t)(c0 + row)*C_DIM + k0 + ch*4);
            short4v s;
            s[0] = (short)f2bf(wv.x); s[1] = (short)f2bf(wv.y);
            s[2] = (short)f2bf(wv.z); s[3] = (short)f2bf(wv.w);
            *(short4v*)&Bws[row][ch*4] = s;
        }
        __syncthreads();
        short8v af[4], bfv[4];
        #pragma unroll
        for (int mt = 0; mt < 4; ++mt)
            af[mt] = *(const short8v*)&Axs[mh + mt*16 + la][lb*8];
        #pragma unroll
        for (int ct = 0; ct < 4; ++ct)
            bfv[ct] = *(const short8v*)&Bws[chh + ct*16 + la][lb*8];
        #pragma unroll
        for (int mt = 0; mt < 4; ++mt)
            #pragma unroll
            for (int ct = 0; ct < 4; ++ct)
                acc[mt][ct] = mfma16(af[mt], bfv[ct], acc[mt][ct]);
        __syncthreads();
    }
    #pragma unroll
    for (int ct = 0; ct < 4; ++ct) {
        const int c = c0 + chh + ct*16 + la;
        const float bias = bvv[c];
        #pragma unroll
        for (int mt = 0; mt < 4; ++mt) {
            const int m = m0 + mh + mt*16 + lb*4;
            short4v s;
            #pragma unroll
            for (int r = 0; r < 4; ++r) s[r] = (short)f2bf(acc[mt][ct][r] + bias);
            *(short4v*)(vbf + ((size_t)b*C_DIM + c)*N_DIM + m) = s;
        }
    }
}

// ---------------------------------------------------------------------------
// Fused attention — R6's validated math, restructured for async memory:
//  P0: prefetch V frags (this iter) + K tile (next iter) into REGISTERS
//  P1: energy MFMA  -> S      | BAR (raw, keeps prefetch in flight)
//  P2: softmax      -> Pb     | BAR
//  P3: rescale + PV (V from regs; hw waits counted vmcnt here)  | BAR
//  P4: write K regs -> LDS for next iter                        | BAR
// __launch_bounds__(256,2): allow up to 256 VGPRs (no spill), same occupancy
// bucket as R6's 132 VGPRs -> prefetch registers are free.
// ---------------------------------------------------------------------------
__global__ __launch_bounds__(256, 2) void attn_mfma(
    const unsigned short* __restrict__ qkt,  // [b][4][1024][64]
    const unsigned short* __restrict__ vbf,  // [b][512][1024]
    const float* __restrict__ x,
    const float* __restrict__ alpha_p,
    float* __restrict__ out)
{
    __shared__ unsigned short Qh[32][72], Ql[32][72];
    __shared__ unsigned short Kh[64][72], Kl[64][72];
    __shared__ __align__(16) float S[32][68];
    __shared__ unsigned short Pb[32][72];
    __shared__ float row_m[32], row_l[32], row_scale[32];

    const int id  = blockIdx.x;
    const int lin = (id & 7) * 128 + (id >> 3);   // XCD-contiguous (1024%8==0)
    const int b   = lin >> 5;
    const int n0  = (lin & 31) * 32;

    const int t = threadIdx.x, w = t >> 6, l = t & 63;
    const int la = l & 15, lb = l >> 4;
    const unsigned short* qkb = qkt + (size_t)b * 4 * N_DIM * 64;

    // ---- Q tile (both planes) -> LDS. Full coverage: 2 planes x 256 loads.
    #pragma unroll
    for (int plane = 0; plane < 2; ++plane) {
        const int row = t >> 3;                // 0..31
        const int ch  = t & 7;                 // 0..7  (8 shorts each)
        const short8v g = *(const short8v*)(qkb + ((size_t)plane*N_DIM + n0 + row)*64 + ch*8);
        if (plane == 0) *(short8v*)&Qh[row][ch*8] = g;
        else            *(short8v*)&Ql[row][ch*8] = g;
    }
    // ---- prologue K stage (tile 0) direct to LDS. Full coverage.
    #pragma unroll
    for (int pp = 0; pp < 4; ++pp) {
        const int plane = pp >> 1;
        const int idx   = t + 256 * (pp & 1);   // 0..511 per plane
        const int row   = idx >> 3;             // 0..63
        const int ch    = idx & 7;              // 0..7
        const short8v g = *(const short8v*)(qkb + ((size_t)(2 + plane)*N_DIM + row)*64 + ch*8);
        if (plane == 0) *(short8v*)&Kh[row][ch*8] = g;
        else            *(short8v*)&Kl[row][ch*8] = g;
    }
    if (t < 32) { row_m[t] = NEG_BIG; row_l[t] = 0.0f; row_scale[t] = 1.0f; }
    __syncthreads();   // prologue: full drain is fine (once)

    floatx4 acc[2][8];   // [ntile][ctile]; n = nt*16+lb*4+r, c = w*128+ct*16+la
    #pragma unroll
    for (int i = 0; i < 2; ++i)
        #pragma unroll
        for (int j = 0; j < 8; ++j) acc[i][j] = (floatx4)0.0f;

    #pragma unroll 1
    for (int it = 0; it < 16; ++it) {
        const int m0  = it * 64;
        const int m0n = (it < 15) ? (m0 + 64) : 0;   // next K tile (wrap: unused)

        // ---- P0: issue prefetch loads (no waits here)
        short8v vreg[2][8];                     // V frags for THIS iter
        #pragma unroll
        for (int ks = 0; ks < 2; ++ks) {
            const unsigned short* vp =
                vbf + ((size_t)b*C_DIM + w*128 + la)*N_DIM + m0 + ks*32 + lb*8;
            #pragma unroll
            for (int ct = 0; ct < 8; ++ct)
                vreg[ks][ct] = *(const short8v*)(vp + (size_t)ct*16*N_DIM);
        }
        short8v kreg[4];                        // K tile for NEXT iter
        #pragma unroll
        for (int pp = 0; pp < 4; ++pp) {
            const int plane = pp >> 1;
            const int idx   = t + 256 * (pp & 1);
            const int row   = idx >> 3;
            const int ch    = idx & 7;
            kreg[pp] = *(const short8v*)(qkb + ((size_t)(2 + plane)*N_DIM + m0n + row)*64 + ch*8);
        }

        // ---- P1: energy MFMA (K tile m0 from LDS); split-bf16 3 terms
        {
            floatx4 e[2] = { (floatx4)0.0f, (floatx4)0.0f };
            #pragma unroll
            for (int ks = 0; ks < 2; ++ks) {
                const short8v ah = *(const short8v*)&Kh[w*16 + la][ks*32 + lb*8];
                const short8v al = *(const short8v*)&Kl[w*16 + la][ks*32 + lb*8];
                #pragma unroll
                for (int nt = 0; nt < 2; ++nt) {
                    const short8v bh = *(const short8v*)&Qh[nt*16 + la][ks*32 + lb*8];
                    const short8v bl = *(const short8v*)&Ql[nt*16 + la][ks*32 + lb*8];
                    e[nt] = mfma16(ah, bh, e[nt]);
                    e[nt] = mfma16(ah, bl, e[nt]);
                    e[nt] = mfma16(al, bh, e[nt]);
                }
            }
            #pragma unroll
            for (int nt = 0; nt < 2; ++nt) {   // D[m][n] -> S[n][m]
                floatx4 ev = e[nt];
                #pragma unroll
                for (int r = 0; r < 4; ++r) ev[r] = fin(ev[r]);
                *(floatx4*)&S[nt*16 + la][w*16 + lb*4] = ev;
            }
        }
        BAR_LDS();   // B1

        // ---- P2: online softmax (R1-proven structure), emit P as bf16
        {
            const int row = t >> 3, seg = t & 7;
            const float4 sa = *(const float4*)&S[row][seg*8];
            const float4 sb = *(const float4*)&S[row][seg*8 + 4];
            float mx = fmaxf(fmaxf(fmaxf(sa.x,sa.y), fmaxf(sa.z,sa.w)),
                             fmaxf(fmaxf(sb.x,sb.y), fmaxf(sb.z,sb.w)));
            mx = fmaxf(mx, __shfl_xor(mx, 1));
            mx = fmaxf(mx, __shfl_xor(mx, 2));
            mx = fmaxf(mx, __shfl_xor(mx, 4));
            const float m_old = row_m[row];
            const float m_new = fmaxf(m_old, mx);
            const float p0 = exp2f((sa.x - m_new) * LOG2E);
            const float p1 = exp2f((sa.y - m_new) * LOG2E);
            const float p2 = exp2f((sa.z - m_new) * LOG2E);
            const float p3 = exp2f((sa.w - m_new) * LOG2E);
            const float p4 = exp2f((sb.x - m_new) * LOG2E);
            const float p5 = exp2f((sb.y - m_new) * LOG2E);
            const float p6 = exp2f((sb.z - m_new) * LOG2E);
            const float p7 = exp2f((sb.w - m_new) * LOG2E);
            float sum = ((p0+p1)+(p2+p3)) + ((p4+p5)+(p6+p7));
            sum += __shfl_xor(sum, 1);
            sum += __shfl_xor(sum, 2);
            sum += __shfl_xor(sum, 4);
            short8v pk;
            pk[0]=(short)f2bf(p0); pk[1]=(short)f2bf(p1);
            pk[2]=(short)f2bf(p2); pk[3]=(short)f2bf(p3);
            pk[4]=(short)f2bf(p4); pk[5]=(short)f2bf(p5);
            pk[6]=(short)f2bf(p6); pk[7]=(short)f2bf(p7);
            *(short8v*)&Pb[row][seg*8] = pk;
            if (seg == 0) {
                const float sc = exp2f((m_old - m_new) * LOG2E);
                row_scale[row] = sc;
                row_l[row] = row_l[row] * sc + sum;
                row_m[row] = m_new;
            }
        }
        BAR_LDS();   // B2

        // ---- P3: rescale accumulators + PV MFMA (V from prefetch regs)
        {
            float fsc[2][4];
            #pragma unroll
            for (int nt = 0; nt < 2; ++nt)
                #pragma unroll
                for (int r = 0; r < 4; ++r) fsc[nt][r] = row_scale[nt*16 + lb*4 + r];
            #pragma unroll
            for (int nt = 0; nt < 2; ++nt)
                #pragma unroll
                for (int ct = 0; ct < 8; ++ct)
                    #pragma unroll
                    for (int r = 0; r < 4; ++r) acc[nt][ct][r] *= fsc[nt][r];
        }
        #pragma unroll
        for (int ks = 0; ks < 2; ++ks) {
            const short8v pa0 = *(const short8v*)&Pb[la][ks*32 + lb*8];
            const short8v pa1 = *(const short8v*)&Pb[16 + la][ks*32 + lb*8];
            #pragma unroll
            for (int ct = 0; ct < 8; ++ct) {
                acc[0][ct] = mfma16(pa0, vreg[ks][ct], acc[0][ct]);
                acc[1][ct] = mfma16(pa1, vreg[ks][ct], acc[1][ct]);
            }
        }
        BAR_LDS();   // B3 (reads consumed by MFMAs above; protects Pb/S reuse)

        // ---- P4: write prefetched K tile -> LDS for next iteration
        #pragma unroll
        for (int pp = 0; pp < 4; ++pp) {
            const int plane = pp >> 1;
            const int idx   = t + 256 * (pp & 1);
            const int row   = idx >> 3;
            const int ch    = idx & 7;
            if (plane == 0) *(short8v*)&Kh[row][ch*8] = kreg[pp];
            else            *(short8v*)&Kl[row][ch*8] = kreg[pp];
        }
        BAR_LDS();   // B4
    }

    // ---- epilogue: out = alpha*acc/l + x (sanitized; output always finite)
    const float alpha = alpha_p[0];
    float invl[2][4];
    #pragma unroll
    for (int nt = 0; nt < 2; ++nt)
        #pragma unroll
        for (int r = 0; r < 4; ++r)
            invl[nt][r] = alpha / fmaxf(row_l[nt*16 + lb*4 + r], 1.0e-20f);
    #pragma unroll
    for (int nt = 0; nt < 2; ++nt)
        #pragma unroll
        for (int ct = 0; ct < 8; ++ct) {
            const int c = w*128 + ct*16 + la;
            const size_t base = ((size_t)b*C_DIM + c)*N_DIM + n0 + nt*16 + lb*4;
            const float4 xa = *(const float4*)&x[base];
            float4 o;
            o.x = fmaf(fin(acc[nt][ct][0]), invl[nt][0], xa.x);
            o.y = fmaf(fin(acc[nt][ct][1]), invl[nt][1], xa.y);
            o.z = fmaf(fin(acc[nt][ct][2]), invl[nt][2], xa.z);
            o.w = fmaf(fin(acc[nt][ct][3]), invl[nt][3], xa.w);
            *(float4*)&out[base] = o;
        }
}

// ---------------------------------------------------------------------------
// Workspace (exactly 80 MiB, the proven footprint):
//   [ 0:32M) xth bf16 [b][1024][512]
//   [32:64M) xtl bf16 [b][1024][512]  -> dead after qkproj; ALIASED by vbf
//   [64:80M) qkt bf16 [b][4][1024][64]
// Order: tx2 -> qkproj (reads xtl) -> vproj (overwrites xtl w/ vbf) -> attn.
// ---------------------------------------------------------------------------
extern "C" void kernel_launch(void* const* d_in, const int* in_sizes, int n_in,
                              void* d_out, int out_size, void* d_ws, size_t ws_size,
                              hipStream_t stream)
{
    const float* x     = (const float*)d_in[0];
    const float* Wq    = (const float*)d_in[1];
    const float* bq    = (const float*)d_in[2];
    const float* Wk    = (const float*)d_in[3];
    const float* bk    = (const float*)d_in[4];
    const float* Wv    = (const float*)d_in[5];
    const float* bv    = (const float*)d_in[6];
    const float* alpha = (const float*)d_in[7];
    float* out = (float*)d_out;

    unsigned short* xth = (unsigned short*)d_ws;
    unsigned short* xtl = (unsigned short*)((char*)d_ws + ((size_t)32 << 20));
    unsigned short* vbf = xtl;   // aliases xtl (dead after qkproj; stream-ordered)
    unsigned short* qkt = (unsigned short*)((char*)d_ws + ((size_t)64 << 20));

    tx2_kernel <<<dim3(16, 8, B_DIM), 256, 0, stream>>>(x, xth, xtl);
    qkproj_mfma<<<dim3(8, 1, B_DIM), 256, 0, stream>>>(xth, xtl, Wq, bq, Wk, bk, qkt);
    vproj_mfma <<<dim3(8, 4, B_DIM), 256, 0, stream>>>(xth, Wv, bv, vbf);
    attn_mfma  <<<dim3(B_DIM * 32), 256, 0, stream>>>(qkt, vbf, x, alpha, out);
}